// Round 9
// baseline (184.439 us; speedup 1.0000x reference)
//
#include <hip/hip_runtime.h>

// PhysicsConstrainedLoss: 6 loss terms over 6.4M edges / 200K nodes.
// R8: p1 software-pipelined. __syncthreads() drains vmcnt(0) on gfx950, so
// R7's per-block loads were fully latency-exposed. Now: 625 blocks x 512 thr,
// 10 tiles x 1024 edges per block; each tile issues the NEXT tile's idx+stream
// loads before its sort barriers, and barriers are raw lgkmcnt(0)+s_barrier
// (vmcnt left in flight -- the verified 8-phase-GEMM sync pattern). Gathers
// issue at tile top from the L2-resident compact nfc table. Downstream
// (pairs slots, offset tables, p2, node, finalize) identical to R7.

constexpr int   kNodes        = 200000;
constexpr int   kEdges        = 6400000;
constexpr int   kNumSums      = 9;
constexpr float kEps          = 1e-6f;

constexpr int   kBucketShift  = 12;                  // 4096 nodes / bucket
constexpr int   kBucketSize   = 1 << kBucketShift;
constexpr int   kBuckets      = (kNodes + kBucketSize - 1) / kBucketSize;  // 49
constexpr int   kThreads      = 512;
constexpr int   kTileEdges    = 1024;                // 2 edges/thread
constexpr int   kTilesPerBlk  = 10;
constexpr int   kP1Blocks     = kEdges / (kTileEdges * kTilesPerBlk);  // 625
constexpr int   kTiles        = kEdges / kTileEdges; // 6250
static_assert(kEdges == kP1Blocks * kTilesPerBlk * kTileEdges, "exact tiling");
constexpr int   kTileEnt      = 2 * kTileEdges;      // 2048 entries/tile
constexpr int   kOffStride    = 52;                  // uint16 stride per tile
constexpr int   kSlabs        = 16;
constexpr int   kTilesPerSlab = (kTiles + kSlabs - 1) / kSlabs;  // 391
constexpr int   kP2Blocks     = kBuckets * kSlabs;   // 784
constexpr int   kNodeBlocks   = 256;
constexpr int   kFbBlocks     = 2048;
constexpr float kQScale       = 65536.0f;
constexpr float kQInv         = 1.0f / 65536.0f;
constexpr int   kQBias        = 524288;              // int20 bias

__device__ __forceinline__ float softplusf(float t) {
    return fmaxf(t, 0.0f) + log1pf(expf(-fabsf(t)));
}

// Workgroup barrier that does NOT drain vmcnt: LDS ops complete, global
// loads stay in flight (8-phase template pattern; memory-clobber asm pins
// surrounding memory ops on both sides).
__device__ __forceinline__ void wg_barrier_lds() {
    asm volatile("s_waitcnt lgkmcnt(0)" ::: "memory");
    __builtin_amdgcn_s_barrier();
    asm volatile("" ::: "memory");
}

// ---------------------------------------------------------------- pre-pass
__global__ __launch_bounds__(256) void compact_nf(
    const float4* __restrict__ nf4,   // (N,4)
    float2*       __restrict__ nfc)   // (N,) packed {vr, vi}
{
    const int i = blockIdx.x * 256 + threadIdx.x;
    if (i < kNodes) {
        const float4 v = nf4[i];
        nfc[i] = make_float2(v.x, v.y);
    }
}

// ---------------------------------------------------------------- phase 1
__global__ __launch_bounds__(kThreads) void p1_edges(
    const float2* __restrict__ nfc,     // compact (N,) {vr,vi}
    const float*  __restrict__ logits,
    const float*  __restrict__ eparams,
    const float*  __restrict__ labels,
    const float*  __restrict__ tparams,
    const int*    __restrict__ srcs,
    const int*    __restrict__ dsts,
    unsigned*       __restrict__ pairs,    // (kTiles, kTileEnt)
    unsigned short* __restrict__ offs_g,   // (kTiles, kOffStride)
    float*          __restrict__ partials) // (kP1Blocks, kNumSums)
{
    __shared__ __align__(16) unsigned sorted[kTileEnt];  // 8 KB
    __shared__ int   hist[kBuckets];
    __shared__ int   offs[kBuckets + 1];
    __shared__ int   cursor[kBuckets];
    __shared__ float smem[kThreads / 64][kNumSums];

    const int tid = threadIdx.x;
    const int g0  = blockIdx.x * kTilesPerBlk;

    const float2* logits2  = reinterpret_cast<const float2*>(logits);
    const float2* labels2  = reinterpret_cast<const float2*>(labels);
    const float4* eparams4 = reinterpret_cast<const float4*>(eparams);
    const float4* tparams4 = reinterpret_cast<const float4*>(tparams);
    const int2*   srcs2    = reinterpret_cast<const int2*>(srcs);
    const int2*   dsts2    = reinterpret_cast<const int2*>(dsts);

    float acc[kNumSums];
#pragma unroll
    for (int k = 0; k < kNumSums; ++k) acc[k] = 0.0f;

    if (tid < kBuckets) hist[tid] = 0;
    __syncthreads();

    // ---- prefetch tile 0 (thread owns edge-pair pi -> edges 2pi, 2pi+1)
    {
        const int pi = g0 * (kTileEdges / 2) + tid;
        // loads issued here; waits happen at first use inside the loop
    }
    int pi0 = g0 * (kTileEdges / 2) + tid;
    int2   nss = srcs2[pi0];
    int2   ndd = dsts2[pi0];
    float2 nlx = logits2[pi0];
    float2 nly = labels2[pi0];
    float4 nea = eparams4[pi0];
    float4 nta = tparams4[pi0];

#pragma unroll 1
    for (int t = 0; t < kTilesPerBlk; ++t) {
        const int g = g0 + t;

        // rotate prefetched registers
        const int2   css = nss;  const int2   cdd = ndd;
        const float2 clx = nlx;  const float2 cly = nly;
        const float4 cea = nea;  const float4 cta = nta;

        // gathers for this tile (depend only on css/cdd)
        const float2 vs0 = nfc[css.x];
        const float2 vs1 = nfc[css.y];
        const float2 vd0 = nfc[cdd.x];
        const float2 vd1 = nfc[cdd.y];

        // issue NEXT tile's idx+stream loads; they stay in flight across
        // this tile's barriers (wg_barrier_lds never drains vmcnt)
        if (t + 1 < kTilesPerBlk) {
            const int pn = (g + 1) * (kTileEdges / 2) + tid;
            nss = srcs2[pn];  ndd = dsts2[pn];
            nlx = logits2[pn]; nly = labels2[pn];
            nea = eparams4[pn]; nta = tparams4[pn];
        }

        unsigned ent[4];
        unsigned bpack = 0;

#pragma unroll
        for (int j = 0; j < 2; ++j) {
            const float x   = (j == 0) ? clx.x : clx.y;
            const float y   = (j == 0) ? cly.x : cly.y;
            const float er  = (j == 0) ? cea.x : cea.z;
            const float ex  = (j == 0) ? cea.y : cea.w;
            const float tr  = (j == 0) ? cta.x : cta.z;
            const float tx  = (j == 0) ? cta.y : cta.w;
            const int   s   = (j == 0) ? css.x : css.y;
            const int   d   = (j == 0) ? cdd.x : cdd.y;
            const float2 vs = (j == 0) ? vs0 : vs1;
            const float2 vd = (j == 0) ? vd0 : vd1;

            // fused sigmoid + BCE, native transcendentals
            const float tt     = __expf(-fabsf(x));
            const float inv1pt = __builtin_amdgcn_rcpf(1.0f + tt);
            const float p      = (x >= 0.0f) ? inv1pt : tt * inv1pt;
            const float sp_nx  = fmaxf(-x, 0.0f) + __logf(1.0f + tt);
            const float bce    = sp_nx + (1.0f - y) * x;

            const float dr  = er - tr;
            const float dxx = ex - tx;

            const float dvr = vs.x - vd.x;
            const float dvi = vs.y - vd.y;
            const float mag = sqrtf(dvr * dvr + dvi * dvi);

            const float Rp    = er + kEps;
            const float curp  = mag * rsqrtf(Rp * Rp + ex * ex) * p;
            const float vdrop = mag * p;

            acc[0] += bce;
            acc[1] += dr * dr + dxx * dxx;
            acc[2] += p;
            acc[3] += p * er;
            acc[4] += p * ex;
            acc[5] += p * er * er;
            acc[6] += p * ex * ex;
            acc[7] += vdrop;
            acc[8] += vdrop * vdrop;

            int q = __float2int_rn(curp * kQScale);
            q = max(-(kQBias - 1), min(kQBias - 1, q));

            const int bd = d >> kBucketShift;
            const int bs = s >> kBucketShift;
            atomicAdd(&hist[bd], 1);
            atomicAdd(&hist[bs], 1);

            ent[2 * j]     = ((unsigned)(d & (kBucketSize - 1)) << 20) | (unsigned)( q + kQBias);
            ent[2 * j + 1] = ((unsigned)(s & (kBucketSize - 1)) << 20) | (unsigned)(-q + kQBias);
            bpack |= ((unsigned)bd) << (16 * j);
            bpack |= ((unsigned)bs) << (16 * j + 8);
        }

        wg_barrier_lds();   // B1: histogram complete

        if (tid < 64) {
            const int lane = tid;
            int h    = (lane < kBuckets) ? hist[lane] : 0;
            int incl = h;
#pragma unroll
            for (int o = 1; o < 64; o <<= 1) {
                int n = __shfl_up(incl, o, 64);
                if (lane >= o) incl += n;
            }
            if (lane < kBuckets) {
                offs[lane]   = incl - h;
                cursor[lane] = 0;
            }
            if (lane == 0) offs[kBuckets] = kTileEnt;
        }

        wg_barrier_lds();   // B2: offs/cursor visible

        // scatter 4 entries -> bucket-sorted LDS; reset hist for next tile
        {
            const int b0 = (int)((bpack >>  0) & 0xFFu);
            const int b1 = (int)((bpack >>  8) & 0xFFu);
            const int b2 = (int)((bpack >> 16) & 0xFFu);
            const int b3 = (int)((bpack >> 24) & 0xFFu);
            int p0 = offs[b0] + atomicAdd(&cursor[b0], 1);
            sorted[p0] = ent[0];
            int p1 = offs[b1] + atomicAdd(&cursor[b1], 1);
            sorted[p1] = ent[1];
            int p2 = offs[b2] + atomicAdd(&cursor[b2], 1);
            sorted[p2] = ent[2];
            int p3 = offs[b3] + atomicAdd(&cursor[b3], 1);
            sorted[p3] = ent[3];
        }
        if (tid < kBuckets) hist[tid] = 0;   // scan already consumed hist

        wg_barrier_lds();   // B3: sorted complete, hist reset done

        // coalesced copy-out: 2048 entries, one uint4 per thread
        {
            const uint4 v = *reinterpret_cast<const uint4*>(&sorted[tid * 4]);
            reinterpret_cast<uint4*>(pairs + (size_t)g * kTileEnt)[tid] = v;
        }
        if (tid < kBuckets + 1)
            offs_g[(size_t)g * kOffStride + tid] = (unsigned short)offs[tid];
        // copy-out's LDS reads complete at next B1; its global stores drain
        // lazily under the next tile's compute.
    }

    // ---- block reduction of the 9 scalar sums
    __syncthreads();
    const int lane = tid & 63;
    const int wave = tid >> 6;
#pragma unroll
    for (int k = 0; k < kNumSums; ++k) {
        float v = acc[k];
#pragma unroll
        for (int off = 32; off > 0; off >>= 1) v += __shfl_down(v, off, 64);
        if (lane == 0) smem[wave][k] = v;
    }
    __syncthreads();
    if (tid < kNumSums) {
        float v = 0.0f;
#pragma unroll
        for (int w = 0; w < kThreads / 64; ++w) v += smem[w][tid];
        partials[blockIdx.x * kNumSums + tid] = v;
    }
}

// ---------------------------------------------------------------- phase 2
__global__ __launch_bounds__(256) void p2_buckets(
    const unsigned*       __restrict__ pairs,
    const unsigned short* __restrict__ offs_g,
    int*                  __restrict__ out_i32)  // (kP2Blocks, kBucketSize)
{
    __shared__ int accs[kBucketSize];
    const int b    = blockIdx.x / kSlabs;
    const int slab = blockIdx.x % kSlabs;

    for (int i = threadIdx.x; i < kBucketSize; i += 256) accs[i] = 0;
    __syncthreads();

    const int i0 = slab * kTilesPerSlab;
    const int i1 = min(i0 + kTilesPerSlab, kTiles);
    const int lane = threadIdx.x & 63;
    const int wave = threadIdx.x >> 6;

    // each wave walks one tile's run for this bucket
    for (int i = i0 + wave; i < i1; i += 4) {
        const int o0 = (int)offs_g[(size_t)i * kOffStride + b];
        const int o1 = (int)offs_g[(size_t)i * kOffStride + b + 1];
        const unsigned* pb = pairs + (size_t)i * kTileEnt;
        for (int j = o0 + lane; j < o1; j += 64) {
            const unsigned u = pb[j];
            atomicAdd(&accs[u >> 20], (int)(u & 0xFFFFFu) - kQBias);
        }
    }
    __syncthreads();

    int* o = out_i32 + (size_t)blockIdx.x * kBucketSize;
    for (int i = threadIdx.x; i < kBucketSize; i += 256) o[i] = accs[i];
}

// ---------------------------------------------------------------- node pass
__global__ __launch_bounds__(256) void node_pass_binned(
    const int* __restrict__ out_i32,
    float*     __restrict__ node_partials)
{
    float acc = 0.0f;
    const int stride = gridDim.x * blockDim.x;
    for (int n = blockIdx.x * blockDim.x + threadIdx.x; n < kNodes; n += stride) {
        const int b = n >> kBucketShift;
        const int s = n & (kBucketSize - 1);
        const int* p = out_i32 + ((size_t)b * kSlabs) * kBucketSize + s;
        int v = 0;
#pragma unroll
        for (int m = 0; m < kSlabs; ++m) v += p[(size_t)m * kBucketSize];
        const float nc = (float)v * kQInv;
        acc += nc * nc;
    }
    __shared__ float smem[4];
    const int lane = threadIdx.x & 63;
    const int wave = threadIdx.x >> 6;
    float v = acc;
#pragma unroll
    for (int off = 32; off > 0; off >>= 1) v += __shfl_down(v, off, 64);
    if (lane == 0) smem[wave] = v;
    __syncthreads();
    if (threadIdx.x == 0)
        node_partials[blockIdx.x] = smem[0] + smem[1] + smem[2] + smem[3];
}

// ---------------------------------------------------------------- fallback (atomic path)
__global__ __launch_bounds__(256) void edge_pass_atomic(
    const float* __restrict__ nf, const float* __restrict__ logits,
    const float* __restrict__ eparams, const float* __restrict__ labels,
    const float* __restrict__ tparams, const int* __restrict__ srcs,
    const int* __restrict__ dsts, float* __restrict__ node_cur,
    float* __restrict__ partials)
{
    float acc[kNumSums];
#pragma unroll
    for (int k = 0; k < kNumSums; ++k) acc[k] = 0.0f;
    const int stride = gridDim.x * blockDim.x;
    for (int e = blockIdx.x * blockDim.x + threadIdx.x; e < kEdges; e += stride) {
        float  x  = logits[e];
        float  y  = labels[e];
        float2 ep = *reinterpret_cast<const float2*>(eparams + 2 * e);
        float2 tp = *reinterpret_cast<const float2*>(tparams + 2 * e);
        int    s  = srcs[e];
        int    d  = dsts[e];
        float2 vs = *reinterpret_cast<const float2*>(nf + 4 * s);
        float2 vd = *reinterpret_cast<const float2*>(nf + 4 * d);
        float p   = 1.0f / (1.0f + expf(-x));
        float bce = y * softplusf(-x) + (1.0f - y) * softplusf(x);
        float dr = ep.x - tp.x, dxx = ep.y - tp.y;
        float dvr = vs.x - vd.x, dvi = vs.y - vd.y;
        float mag = sqrtf(dvr * dvr + dvi * dvi);
        float Rp  = ep.x + kEps;
        float den = sqrtf(Rp * Rp + ep.y * ep.y);
        float curp = (mag / den) * p;
        float vdrop = mag * p;
        acc[0] += bce; acc[1] += dr * dr + dxx * dxx; acc[2] += p;
        acc[3] += p * ep.x; acc[4] += p * ep.y;
        acc[5] += p * ep.x * ep.x; acc[6] += p * ep.y * ep.y;
        acc[7] += vdrop; acc[8] += vdrop * vdrop;
        atomicAdd(node_cur + d,  curp);
        atomicAdd(node_cur + s, -curp);
    }
    __shared__ float smem[4][kNumSums];
    const int lane = threadIdx.x & 63, wave = threadIdx.x >> 6;
#pragma unroll
    for (int k = 0; k < kNumSums; ++k) {
        float v = acc[k];
#pragma unroll
        for (int off = 32; off > 0; off >>= 1) v += __shfl_down(v, off, 64);
        if (lane == 0) smem[wave][k] = v;
    }
    __syncthreads();
    if (threadIdx.x < kNumSums) {
        float v = 0.0f;
#pragma unroll
        for (int w = 0; w < 4; ++w) v += smem[w][threadIdx.x];
        partials[blockIdx.x * kNumSums + threadIdx.x] = v;
    }
}

__global__ __launch_bounds__(256) void node_pass_flat(
    const float* __restrict__ node_cur, float* __restrict__ node_partials)
{
    float acc = 0.0f;
    const int stride = gridDim.x * blockDim.x;
    for (int i = blockIdx.x * blockDim.x + threadIdx.x; i < kNodes; i += stride) {
        float v = node_cur[i];
        acc += v * v;
    }
    __shared__ float smem[4];
    const int lane = threadIdx.x & 63, wave = threadIdx.x >> 6;
    float v = acc;
#pragma unroll
    for (int off = 32; off > 0; off >>= 1) v += __shfl_down(v, off, 64);
    if (lane == 0) smem[wave] = v;
    __syncthreads();
    if (threadIdx.x == 0)
        node_partials[blockIdx.x] = smem[0] + smem[1] + smem[2] + smem[3];
}

// ---------------------------------------------------------------- finalize
__global__ __launch_bounds__(256) void finalize(
    const float* __restrict__ partials, int nblocks,
    const float* __restrict__ node_partials, int nnp,
    float*       __restrict__ out)
{
    const int tid  = threadIdx.x;
    const int lane = tid & 63;
    const int wave = tid >> 6;
    __shared__ double red[4][kNumSums + 1];

    double s[kNumSums];
#pragma unroll
    for (int k = 0; k < kNumSums; ++k) s[k] = 0.0;
    for (int i = tid; i < nblocks; i += 256) {
#pragma unroll
        for (int k = 0; k < kNumSums; ++k)
            s[k] += (double)partials[i * kNumSums + k];
    }
    double ns = 0.0;
    for (int i = tid; i < nnp; i += 256) ns += (double)node_partials[i];

#pragma unroll
    for (int k = 0; k < kNumSums + 1; ++k) {
        double v = (k < kNumSums) ? s[k] : ns;
#pragma unroll
        for (int off = 32; off > 0; off >>= 1) v += __shfl_down(v, off, 64);
        if (lane == 0) red[wave][k] = v;
    }
    __syncthreads();

    if (tid == 0) {
        double sums[kNumSums + 1];
#pragma unroll
        for (int k = 0; k < kNumSums + 1; ++k)
            sums[k] = red[0][k] + red[1][k] + red[2][k] + red[3][k];

        const double E = (double)kEdges, N = (double)kNodes;
        const double s_bce = sums[0], s_par = sums[1], s_p = sums[2];
        const double s_pR = sums[3], s_pX = sums[4];
        const double s_pR2 = sums[5], s_pX2 = sums[6];
        const double s_v = sums[7], s_v2 = sums[8];
        const double nsum = sums[9];

        double topology  = s_bce / E;
        double parameter = s_par / (2.0 * E);
        double kcl       = 0.1 * (nsum / N);

        double denom = s_p + (double)kEps;
        double mR = s_pR / denom, mX = s_pX / denom;
        double varR = s_pR2 - 2.0 * mR * s_pR + mR * mR * s_p;
        double varX = s_pX2 - 2.0 * mX * s_pX + mX * mX * s_p;
        double param_consistency = 0.5 * (varR + varX);
        double voltage_consistency = (s_v2 - (s_v * s_v) / E) / (E - 1.0);
        double kvl = 0.1 * (param_consistency + voltage_consistency);

        double ecl = s_p - (N - 1.0);
        ecl = ecl * ecl;
        double radial   = 0.1 * (ecl + 0.1 * (s_p / E));
        double sparsity = 0.01 * (s_p / E);
        double total = topology + parameter + kcl + kvl + radial + sparsity;

        out[0] = (float)topology;  out[1] = (float)parameter;
        out[2] = (float)kcl;       out[3] = (float)kvl;
        out[4] = (float)radial;    out[5] = (float)sparsity;
        out[6] = (float)total;
    }
}

extern "C" void kernel_launch(void* const* d_in, const int* in_sizes, int n_in,
                              void* d_out, int out_size, void* d_ws, size_t ws_size,
                              hipStream_t stream) {
    const float* nf      = (const float*)d_in[0];
    const float* logits  = (const float*)d_in[1];
    const float* eparams = (const float*)d_in[2];
    const float* labels  = (const float*)d_in[3];
    const float* tparams = (const float*)d_in[4];
    const int*   eidx    = (const int*)d_in[5];
    float* out           = (float*)d_out;

    // layout (words): [pairs][out_i32][nfc][offs(u16)][partials][node_partials]
    const size_t n_pairs  = (size_t)kTiles * kTileEnt;                   // 12.8M
    const size_t n_outi32 = (size_t)kP2Blocks * kBucketSize;             // 3.21M
    const size_t n_nfc    = (size_t)kNodes * 2;                          // 400K
    const size_t n_offs_w = ((size_t)kTiles * kOffStride + 1) / 2 + 64;
    const size_t n_words  = n_pairs + n_outi32 + n_nfc + n_offs_w +
                            (size_t)kP1Blocks * kNumSums + kNodeBlocks;

    if (ws_size >= n_words * sizeof(unsigned)) {
        unsigned*       pairs         = (unsigned*)d_ws;
        int*            out_i32       = (int*)(pairs + n_pairs);
        float2*         nfc           = (float2*)(out_i32 + n_outi32);
        unsigned short* offs_g        = (unsigned short*)((unsigned*)nfc + n_nfc);
        float*          partials      = (float*)((unsigned*)offs_g + n_offs_w);
        float*          node_partials = partials + (size_t)kP1Blocks * kNumSums;

        compact_nf<<<(kNodes + 255) / 256, 256, 0, stream>>>(
            (const float4*)nf, nfc);
        p1_edges<<<kP1Blocks, kThreads, 0, stream>>>(nfc, logits, eparams, labels,
                                                     tparams, eidx, eidx + kEdges,
                                                     pairs, offs_g, partials);
        p2_buckets<<<kP2Blocks, 256, 0, stream>>>(pairs, offs_g, out_i32);
        node_pass_binned<<<kNodeBlocks, 256, 0, stream>>>(out_i32, node_partials);
        finalize<<<1, 256, 0, stream>>>(partials, kP1Blocks, node_partials,
                                        kNodeBlocks, out);
    } else {
        float* node_cur      = (float*)d_ws;
        float* partials      = node_cur + kNodes;
        float* node_partials = partials + (size_t)kFbBlocks * kNumSums;

        hipMemsetAsync(node_cur, 0, kNodes * sizeof(float), stream);
        edge_pass_atomic<<<kFbBlocks, 256, 0, stream>>>(nf, logits, eparams, labels,
                                                        tparams, eidx, eidx + kEdges,
                                                        node_cur, partials);
        node_pass_flat<<<kNodeBlocks, 256, 0, stream>>>(node_cur, node_partials);
        finalize<<<1, 256, 0, stream>>>(partials, kFbBlocks, node_partials,
                                        kNodeBlocks, out);
    }
}